// Round 8
// baseline (176.026 us; speedup 1.0000x reference)
//
#include <hip/hip_runtime.h>
#include <hip/hip_bf16.h>

#define N_NODES 50000
#define N_EDGES 640000
#define N_REL   200
#define D       128
#define CAP     64          // bucket capacity per node; max degree ~35 (Poisson 12.8)

typedef __attribute__((ext_vector_type(8))) short short8;   // 8 bf16 (4 VGPRs)
typedef __attribute__((ext_vector_type(4))) float floatx4;  // MFMA acc

__device__ __forceinline__ unsigned short f2bf(float f) {   // RNE f32->bf16
    unsigned u = __float_as_uint(f);
    u += 0x7FFF + ((u >> 16) & 1);
    return (unsigned short)(u >> 16);
}

__device__ __forceinline__ float sigmoidf(float x) {
    return 1.f / (1.f + __expf(-x));
}

// ---------------------------------------------------------------------------
// Kernel 1 (setup, fused by block range):
//   blocks 0..63      : W_lin -> bf16
//   blocks 64..113    : s_rel[r] = dot(rel_emb[r], W_attn)       (200 waves)
//   blocks 114..309   : zero count[]
//   blocks 310..6559  : s_node[n] = dot(x[n], W_attn), half-wave per node
//                       (32 lanes x float4 = 128 dims, coalesced)
// ---------------------------------------------------------------------------
__global__ void setup_kernel(const float* __restrict__ W,
                             const float* __restrict__ x,
                             const float* __restrict__ rel,
                             const float* __restrict__ Wattn,
                             unsigned short* __restrict__ Wbf,
                             float* __restrict__ s_rel,
                             float* __restrict__ s_node,
                             int* __restrict__ count) {
    const int b = blockIdx.x;
    if (b < 64) {
        const int i = b * 256 + threadIdx.x;          // 0..16383
        Wbf[i] = f2bf(W[i]);
    } else if (b < 114) {
        const int wave = (b - 64) * 4 + (threadIdx.x >> 6);
        const int lane = threadIdx.x & 63;
        if (wave < N_REL) {
            const float* __restrict__ row = rel + (size_t)wave * D;
            float a = fmaf(row[lane], Wattn[lane],
                           row[lane + 64] * Wattn[lane + 64]);
#pragma unroll
            for (int off = 32; off; off >>= 1)
                a += __shfl_down(a, off);
            if (lane == 0) s_rel[wave] = a;
        }
    } else if (b < 310) {
        const int i = (b - 114) * 256 + threadIdx.x;
        if (i < N_NODES) count[i] = 0;
    } else {
        const int node = (b - 310) * 8 + (threadIdx.x >> 5);
        const int sub  = threadIdx.x & 31;
        if (node < N_NODES) {
            const float4 xv = ((const float4*)(x + (size_t)node * D))[sub];
            const float4 wv = ((const float4*)Wattn)[sub];
            float a = xv.x * wv.x + xv.y * wv.y + xv.z * wv.z + xv.w * wv.w;
#pragma unroll
            for (int off = 16; off; off >>= 1)
                a += __shfl_xor(a, off);              // stays within 32-lane half
            if (sub == 0) s_node[node] = a;
        }
    }
}

// ---------------------------------------------------------------------------
// Kernel 2 (fused xtrans + scatter, interleaved 1-in-4):
//   blocks with b%4==3 : xtrans via MFMA 16x16x32 bf16 (one wave / 16 nodes)
//   all other blocks   : bucket scatter, 1 edge/thread
// Rationale: scatter is bound by random-sector HBM writeback (~0.8 TB/s,
// invariant to occupancy — R6/R7 evidence); xtrans is compute-bound and
// independent given s_node. Co-residency makes total ~= max, not sum (m114).
// ---------------------------------------------------------------------------
__global__ void fused_kernel(const float* __restrict__ x,
                             const unsigned short* __restrict__ Wbf,
                             unsigned short* __restrict__ xt,
                             const int* __restrict__ src_idx,
                             const int* __restrict__ tgt_idx,
                             const int* __restrict__ etype,
                             const float* __restrict__ s_node,
                             const float* __restrict__ s_rel,
                             int* __restrict__ count,
                             unsigned* __restrict__ sorted) {
    const int b = blockIdx.x;
    if ((b & 3) == 3) {
        // ---- xtrans block (b>>2) in 0..832; 4 waves -> 64 nodes/block ----
        const int wid = (b >> 2) * 4 + (threadIdx.x >> 6);
        if (wid >= N_NODES / 16) return;           // 3125 waves total
        const int lane = threadIdx.x & 63;
        const int r16  = lane & 15;
        const int quad = lane >> 4;
        const int m0   = wid * 16;

        short8 af[4];
#pragma unroll
        for (int s = 0; s < 4; ++s) {
            const int k0 = s * 32 + quad * 8;
            const float* __restrict__ xr = x + (size_t)(m0 + r16) * D + k0;
            const float4 lo = *(const float4*)(xr);
            const float4 hi = *(const float4*)(xr + 4);
            short8 a;
            a[0] = (short)f2bf(lo.x); a[1] = (short)f2bf(lo.y);
            a[2] = (short)f2bf(lo.z); a[3] = (short)f2bf(lo.w);
            a[4] = (short)f2bf(hi.x); a[5] = (short)f2bf(hi.y);
            a[6] = (short)f2bf(hi.z); a[7] = (short)f2bf(hi.w);
            af[s] = a;
        }

#pragma unroll
        for (int t = 0; t < 8; ++t) {
            floatx4 acc = {0.f, 0.f, 0.f, 0.f};
#pragma unroll
            for (int s = 0; s < 4; ++s) {
                const int k0 = s * 32 + quad * 8;
                const short8 bb = *(const short8*)(Wbf + (size_t)(t * 16 + r16) * D + k0);
                acc = __builtin_amdgcn_mfma_f32_16x16x32_bf16(af[s], bb, acc, 0, 0, 0);
            }
#pragma unroll
            for (int r = 0; r < 4; ++r) {
                const int orow = m0 + quad * 4 + r;
                xt[(size_t)orow * D + t * 16 + r16] = f2bf(acc[r]);
            }
        }
    } else {
        // ---- scatter block: sb = b - floor(b/4), 1 edge/thread ----
        const int sb = b - (b >> 2);               // 0..2499
        const int e = sb * 256 + threadIdx.x;
        if (e >= N_EDGES) return;
        const int s = src_idx[e];
        const int t = tgt_idx[e];
        const int r = etype[e];

        const float logit = s_node[s] + s_rel[r];
        const unsigned rec = ((unsigned)f2bf(sigmoidf(logit)) << 16) | (unsigned)s;

        const int k = atomicAdd(&count[t], 1);
        sorted[t * CAP + k] = rec;
    }
}

// ---------------------------------------------------------------------------
// Kernel 3: gather + fused ReLU. TWO nodes per wave; lane owns 4 bf16 dims.
// Records pulled 4-at-a-time (uint4) -> 4 xt row loads in flight.
// ---------------------------------------------------------------------------
__device__ __forceinline__ void gproc(unsigned r, const unsigned short* __restrict__ xt,
                                      int sub, float4& acc) {
    const unsigned src = r & 0xFFFFu;
    const float a = __uint_as_float(r & 0xFFFF0000u);
    const uint2 p = *(const uint2*)(xt + (size_t)src * D + sub * 4);
    acc.x = fmaf(a, __uint_as_float(p.x << 16),        acc.x);
    acc.y = fmaf(a, __uint_as_float(p.x & 0xFFFF0000u), acc.y);
    acc.z = fmaf(a, __uint_as_float(p.y << 16),        acc.z);
    acc.w = fmaf(a, __uint_as_float(p.y & 0xFFFF0000u), acc.w);
}

__global__ void gather_kernel(const int* __restrict__ count,
                              const unsigned* __restrict__ sorted,
                              const unsigned short* __restrict__ xt,
                              float* __restrict__ out) {
    const int wid  = (blockIdx.x * blockDim.x + threadIdx.x) >> 6;
    const int lane = threadIdx.x & 63;
    const int half = lane >> 5;
    const int sub  = lane & 31;
    const int t    = wid * 2 + half;
    if (t >= N_NODES) return;

    const int cnt = count[t];
    const unsigned* __restrict__ rec = sorted + (size_t)t * CAP;

    float4 acc = {0.f, 0.f, 0.f, 0.f};
    int i = 0;
    for (; i + 4 <= cnt; i += 4) {
        const uint4 r4 = *(const uint4*)(rec + i);
        gproc(r4.x, xt, sub, acc);
        gproc(r4.y, xt, sub, acc);
        gproc(r4.z, xt, sub, acc);
        gproc(r4.w, xt, sub, acc);
    }
    for (; i < cnt; ++i)
        gproc(rec[i], xt, sub, acc);

    float4 o;
    o.x = fmaxf(acc.x, 0.f);
    o.y = fmaxf(acc.y, 0.f);
    o.z = fmaxf(acc.z, 0.f);
    o.w = fmaxf(acc.w, 0.f);
    ((float4*)(out + (size_t)t * D))[sub] = o;
}

extern "C" void kernel_launch(void* const* d_in, const int* in_sizes, int n_in,
                              void* d_out, int out_size, void* d_ws, size_t ws_size,
                              hipStream_t stream) {
    const float* x        = (const float*)d_in[0];              // [N, 128]
    const int*   edge_idx = (const int*)d_in[1];                // [2, E]
    const int*   etype    = (const int*)d_in[2];                // [E]
    const float* rel_emb  = (const float*)d_in[3];              // [R, 128]
    const float* W_lin    = (const float*)d_in[4];              // [128, 128]
    const float* W_attn   = (const float*)d_in[5];              // [1, 128]
    float* out = (float*)d_out;                                 // [N, 128]

    const int* src_idx = edge_idx;
    const int* tgt_idx = edge_idx + N_EDGES;

    // workspace layout (~26 MB total)
    unsigned short* xt   = (unsigned short*)d_ws;               // 12.8 MB (bf16)
    float* s_node        = (float*)(xt + (size_t)N_NODES * D);  // 200 KB
    float* s_rel         = s_node + N_NODES;                    // 800 B
    unsigned short* Wbf  = (unsigned short*)(s_rel + N_REL);    // 32 KB (bf16)
    int*   count         = (int*)(Wbf + D * D);                 // 200 KB
    unsigned* sorted     = (unsigned*)(count + N_NODES);        // 12.8 MB

    // 1. setup: W->bf16, s_rel, zero count, s_node   (6560 blocks)
    setup_kernel<<<dim3(310 + (N_NODES + 7) / 8), dim3(256), 0, stream>>>(
        W_lin, x, rel_emb, W_attn, Wbf, s_rel, s_node, count);

    // 2. fused xtrans (MFMA) + bucket scatter, interleaved 1-in-4
    //    T=3333: 833 xtrans slots (need 782), 2500 scatter slots (exact)
    fused_kernel<<<dim3(3333), dim3(256), 0, stream>>>(
        x, Wbf, xt, src_idx, tgt_idx, etype, s_node, s_rel, count, sorted);

    // 3. gather + fused ReLU (2 nodes per wave, 8 nodes per block)
    gather_kernel<<<dim3(N_NODES / 8), dim3(256), 0, stream>>>(
        count, sorted, xt, out);
}

// Round 9
// 169.161 us; speedup vs baseline: 1.0406x; 1.0406x over previous
//
#include <hip/hip_runtime.h>
#include <hip/hip_bf16.h>

#define N_NODES 50000
#define N_EDGES 640000
#define N_REL   200
#define D       128
#define CAP     64              // bucket capacity; max degree ~35 (Poisson 12.8)
#define RANGES  8               // one target-range per XCD
#define NODES_PER_RANGE (N_NODES / RANGES)   // 6250
#define CHUNK_EDGES 2560
#define N_CHUNKS (N_EDGES / CHUNK_EDGES)     // 250

typedef __attribute__((ext_vector_type(8))) short short8;   // 8 bf16 (4 VGPRs)
typedef __attribute__((ext_vector_type(4))) float floatx4;  // MFMA acc

__device__ __forceinline__ unsigned short f2bf(float f) {   // RNE f32->bf16
    unsigned u = __float_as_uint(f);
    u += 0x7FFF + ((u >> 16) & 1);
    return (unsigned short)(u >> 16);
}

__device__ __forceinline__ float sigmoidf(float x) {
    return 1.f / (1.f + __expf(-x));
}

// ---------------------------------------------------------------------------
// Kernel 1 (setup, fused by block range):
//   blocks 0..63      : W_lin -> bf16
//   blocks 64..113    : s_rel[r] = dot(rel_emb[r], W_attn)
//   blocks 114..309   : zero count[]
//   blocks 310..6559  : s_node[n] = dot(x[n], W_attn), half-wave per node
// ---------------------------------------------------------------------------
__global__ void setup_kernel(const float* __restrict__ W,
                             const float* __restrict__ x,
                             const float* __restrict__ rel,
                             const float* __restrict__ Wattn,
                             unsigned short* __restrict__ Wbf,
                             float* __restrict__ s_rel,
                             float* __restrict__ s_node,
                             int* __restrict__ count) {
    const int b = blockIdx.x;
    if (b < 64) {
        const int i = b * 256 + threadIdx.x;          // 0..16383
        Wbf[i] = f2bf(W[i]);
    } else if (b < 114) {
        const int wave = (b - 64) * 4 + (threadIdx.x >> 6);
        const int lane = threadIdx.x & 63;
        if (wave < N_REL) {
            const float* __restrict__ row = rel + (size_t)wave * D;
            float a = fmaf(row[lane], Wattn[lane],
                           row[lane + 64] * Wattn[lane + 64]);
#pragma unroll
            for (int off = 32; off; off >>= 1)
                a += __shfl_down(a, off);
            if (lane == 0) s_rel[wave] = a;
        }
    } else if (b < 310) {
        const int i = (b - 114) * 256 + threadIdx.x;
        if (i < N_NODES) count[i] = 0;
    } else {
        const int node = (b - 310) * 8 + (threadIdx.x >> 5);
        const int sub  = threadIdx.x & 31;
        if (node < N_NODES) {
            const float4 xv = ((const float4*)(x + (size_t)node * D))[sub];
            const float4 wv = ((const float4*)Wattn)[sub];
            float a = xv.x * wv.x + xv.y * wv.y + xv.z * wv.z + xv.w * wv.w;
#pragma unroll
            for (int off = 16; off; off >>= 1)
                a += __shfl_xor(a, off);              // within 32-lane half
            if (sub == 0) s_node[node] = a;
        }
    }
}

// ---------------------------------------------------------------------------
// Kernel 2: xt = x @ W_lin.T via MFMA 16x16x32 bf16 (standalone, lean).
// One wave per 16 nodes, no LDS. Layouts per m89/m120.
// ---------------------------------------------------------------------------
__global__ void xtrans_mfma_kernel(const float* __restrict__ x,
                                   const unsigned short* __restrict__ Wbf,
                                   unsigned short* __restrict__ xt) {
    const int wid = (blockIdx.x * blockDim.x + threadIdx.x) >> 6;
    if (wid >= N_NODES / 16) return;           // 3125 waves exactly
    const int lane = threadIdx.x & 63;
    const int r16  = lane & 15;
    const int quad = lane >> 4;
    const int m0   = wid * 16;

    short8 af[4];
#pragma unroll
    for (int s = 0; s < 4; ++s) {
        const int k0 = s * 32 + quad * 8;
        const float* __restrict__ xr = x + (size_t)(m0 + r16) * D + k0;
        const float4 lo = *(const float4*)(xr);
        const float4 hi = *(const float4*)(xr + 4);
        short8 a;
        a[0] = (short)f2bf(lo.x); a[1] = (short)f2bf(lo.y);
        a[2] = (short)f2bf(lo.z); a[3] = (short)f2bf(lo.w);
        a[4] = (short)f2bf(hi.x); a[5] = (short)f2bf(hi.y);
        a[6] = (short)f2bf(hi.z); a[7] = (short)f2bf(hi.w);
        af[s] = a;
    }

#pragma unroll
    for (int t = 0; t < 8; ++t) {
        floatx4 acc = {0.f, 0.f, 0.f, 0.f};
#pragma unroll
        for (int s = 0; s < 4; ++s) {
            const int k0 = s * 32 + quad * 8;
            const short8 b = *(const short8*)(Wbf + (size_t)(t * 16 + r16) * D + k0);
            acc = __builtin_amdgcn_mfma_f32_16x16x32_bf16(af[s], b, acc, 0, 0, 0);
        }
#pragma unroll
        for (int r = 0; r < 4; ++r) {
            const int orow = m0 + quad * 4 + r;
            xt[(size_t)orow * D + t * 16 + r16] = f2bf(acc[r]);
        }
    }
}

// ---------------------------------------------------------------------------
// Kernel 3: XCD-partitioned bucket scatter.
// Block b: edge chunk (b>>3), target range (b&7). With round-robin block->XCD
// dispatch, all writes of range r stay in XCD r's L2 (1.6 MB slice << 4 MB),
// so no mid-kernel evictions and each dirty line flushes once at kernel end.
// Edges are re-read 8x (coalesced streaming ~61 MB — cheap); correctness is
// independent of the actual block->XCD mapping (every (chunk,range) pair
// processed exactly once).
// ---------------------------------------------------------------------------
__global__ void scatter_kernel(const int* __restrict__ src_idx,
                               const int* __restrict__ tgt_idx,
                               const int* __restrict__ etype,
                               const float* __restrict__ s_node,
                               const float* __restrict__ s_rel,
                               int* __restrict__ count,
                               unsigned* __restrict__ sorted) {
    const int b     = blockIdx.x;
    const int lo    = (b & 7) * NODES_PER_RANGE;
    const int hi    = lo + NODES_PER_RANGE;
    const int base  = (b >> 3) * CHUNK_EDGES + threadIdx.x;

#pragma unroll
    for (int it = 0; it < CHUNK_EDGES / 256; ++it) {
        const int e = base + it * 256;
        const int t = tgt_idx[e];                    // coalesced
        if (t >= lo && t < hi) {
            const int s = src_idx[e];
            const int r = etype[e];
            const float logit = s_node[s] + s_rel[r];
            const unsigned rec =
                ((unsigned)f2bf(sigmoidf(logit)) << 16) | (unsigned)s;
            const int k = atomicAdd(&count[t], 1);
            sorted[t * CAP + k] = rec;               // XCD-local L2 write
        }
    }
}

// ---------------------------------------------------------------------------
// Kernel 4: gather + fused ReLU. TWO nodes per wave; lane owns 4 bf16 dims.
// Records pulled 4-at-a-time (uint4) -> 4 xt row loads in flight.
// ---------------------------------------------------------------------------
__device__ __forceinline__ void gproc(unsigned r, const unsigned short* __restrict__ xt,
                                      int sub, float4& acc) {
    const unsigned src = r & 0xFFFFu;
    const float a = __uint_as_float(r & 0xFFFF0000u);
    const uint2 p = *(const uint2*)(xt + (size_t)src * D + sub * 4);
    acc.x = fmaf(a, __uint_as_float(p.x << 16),        acc.x);
    acc.y = fmaf(a, __uint_as_float(p.x & 0xFFFF0000u), acc.y);
    acc.z = fmaf(a, __uint_as_float(p.y << 16),        acc.z);
    acc.w = fmaf(a, __uint_as_float(p.y & 0xFFFF0000u), acc.w);
}

__global__ void gather_kernel(const int* __restrict__ count,
                              const unsigned* __restrict__ sorted,
                              const unsigned short* __restrict__ xt,
                              float* __restrict__ out) {
    const int wid  = (blockIdx.x * blockDim.x + threadIdx.x) >> 6;
    const int lane = threadIdx.x & 63;
    const int half = lane >> 5;
    const int sub  = lane & 31;
    const int t    = wid * 2 + half;
    if (t >= N_NODES) return;

    const int cnt = count[t];
    const unsigned* __restrict__ rec = sorted + (size_t)t * CAP;

    float4 acc = {0.f, 0.f, 0.f, 0.f};
    int i = 0;
    for (; i + 4 <= cnt; i += 4) {
        const uint4 r4 = *(const uint4*)(rec + i);
        gproc(r4.x, xt, sub, acc);
        gproc(r4.y, xt, sub, acc);
        gproc(r4.z, xt, sub, acc);
        gproc(r4.w, xt, sub, acc);
    }
    for (; i < cnt; ++i)
        gproc(rec[i], xt, sub, acc);

    float4 o;
    o.x = fmaxf(acc.x, 0.f);
    o.y = fmaxf(acc.y, 0.f);
    o.z = fmaxf(acc.z, 0.f);
    o.w = fmaxf(acc.w, 0.f);
    ((float4*)(out + (size_t)t * D))[sub] = o;
}

extern "C" void kernel_launch(void* const* d_in, const int* in_sizes, int n_in,
                              void* d_out, int out_size, void* d_ws, size_t ws_size,
                              hipStream_t stream) {
    const float* x        = (const float*)d_in[0];              // [N, 128]
    const int*   edge_idx = (const int*)d_in[1];                // [2, E]
    const int*   etype    = (const int*)d_in[2];                // [E]
    const float* rel_emb  = (const float*)d_in[3];              // [R, 128]
    const float* W_lin    = (const float*)d_in[4];              // [128, 128]
    const float* W_attn   = (const float*)d_in[5];              // [1, 128]
    float* out = (float*)d_out;                                 // [N, 128]

    const int* src_idx = edge_idx;
    const int* tgt_idx = edge_idx + N_EDGES;

    // workspace layout (~26 MB total)
    unsigned short* xt   = (unsigned short*)d_ws;               // 12.8 MB (bf16)
    float* s_node        = (float*)(xt + (size_t)N_NODES * D);  // 200 KB
    float* s_rel         = s_node + N_NODES;                    // 800 B
    unsigned short* Wbf  = (unsigned short*)(s_rel + N_REL);    // 32 KB (bf16)
    int*   count         = (int*)(Wbf + D * D);                 // 200 KB
    unsigned* sorted     = (unsigned*)(count + N_NODES);        // 12.8 MB

    // 1. setup: W->bf16, s_rel, zero count, s_node
    setup_kernel<<<dim3(310 + (N_NODES + 7) / 8), dim3(256), 0, stream>>>(
        W_lin, x, rel_emb, W_attn, Wbf, s_rel, s_node, count);

    // 2. xt = x @ W_lin.T (MFMA, standalone)
    xtrans_mfma_kernel<<<dim3((N_NODES / 16 * 64 + 255) / 256), dim3(256), 0, stream>>>(
        x, Wbf, xt);

    // 3. XCD-partitioned bucket scatter (2000 blocks = 250 chunks x 8 ranges)
    scatter_kernel<<<dim3(N_CHUNKS * RANGES), dim3(256), 0, stream>>>(
        src_idx, tgt_idx, etype, s_node, s_rel, count, sorted);

    // 4. gather + fused ReLU (2 nodes per wave, 8 nodes per block)
    gather_kernel<<<dim3(N_NODES / 8), dim3(256), 0, stream>>>(
        count, sorted, xt, out);
}